// Round 4
// baseline (65.818 us; speedup 1.0000x reference)
//
#include <hip/hip_runtime.h>
#include <stdint.h>

#define N_ATOMS 8192
#define KNB 32            // MAX_NEIGHBORS
#define CUTOFF_F 5.0f
#define CAP 256           // max supported molecule size (validated R1-R3)

// One 64-thread wave per PAIR of atoms (i0=2B, i1=2B+1). Pairs are almost
// always in the same molecule -> one pos[j]/sqj load serves both distance
// tests. Molecule range found in-wave by ballot-scanning a 256-wide batch
// window (batch sorted -> membership mask is contiguous; popcount gives the
// boundary) — no helper kernel, no dependent binary search. Valid keys
// (dist_bits<<32 | j) are wave-compacted into LDS; rank (#{strictly smaller})
// is the output slot — exact jax.lax.top_k order (ascending dist, lower index
// on ties). Epilogue: 64 lanes write 64 contiguous edges, fully coalesced.
__global__ __launch_bounds__(64) void radius_graph_kernel(
    const float* __restrict__ pos, const int* __restrict__ batch,
    float* __restrict__ out)
{
    const int i0   = blockIdx.x * 2;
    const int i1   = i0 + 1;
    const int lane = threadIdx.x;
    __shared__ uint64_t list0[CAP], list1[CAP];
    __shared__ int win[2][KNB];

    const int b0 = batch[i0];
    const int b1 = batch[i1];

    // start0: ones in window [i0-255, i0] (mask is contiguous ending at i0)
    int ones_below = 0;
    #pragma unroll
    for (int c = 0; c < 4; ++c) {
        const int idx = i0 - 255 + (c << 6) + lane;
        const int v = batch[idx < 0 ? 0 : idx];
        ones_below += __popcll(__ballot(idx >= 0 && v == b0));
    }
    const int start0 = i0 + 1 - ones_below;

    // end0: ones in window [i0, i0+255]
    int ones_above = 0;
    #pragma unroll
    for (int c = 0; c < 4; ++c) {
        const int idx = i0 + (c << 6) + lane;
        const int v = batch[idx > N_ATOMS - 1 ? N_ATOMS - 1 : idx];
        ones_above += __popcll(__ballot(idx < N_ATOMS && v == b0));
    }
    const int end0 = i0 + ones_above;

    int start1, end1;
    if (b1 == b0) { start1 = start0; end1 = end0; }
    else {                                   // rare: molecule boundary inside pair
        start1 = i1;                         // sorted -> i1 is first of its molecule
        int oa = 0;
        #pragma unroll
        for (int c = 0; c < 4; ++c) {
            const int idx = i1 + (c << 6) + lane;
            const int v = batch[idx > N_ATOMS - 1 ? N_ATOMS - 1 : idx];
            oa += __popcll(__ballot(idx < N_ATOMS && v == b1));
        }
        end1 = i1 + oa;
    }

    const float x0 = pos[3 * i0], y0 = pos[3 * i0 + 1], z0 = pos[3 * i0 + 2];
    const float x1 = pos[3 * i1], y1 = pos[3 * i1 + 1], z1 = pos[3 * i1 + 2];
    const float sq0 = x0 * x0 + y0 * y0 + z0 * z0;
    const float sq1 = x1 * x1 + y1 * y1 + z1 * z1;

    // generic single-atom candidate pass (used on the rare split-pair path)
    auto process = [&](int s, int e_, int self, float sx, float sy, float sz,
                       float ssq, uint64_t* lst) -> int {
        int cnt = 0;
        for (int jb = s; jb < e_; jb += 64) {
            const int j = jb + lane;
            bool v = false; uint64_t k = 0;
            if (j < e_ && j != self) {
                const float xj = pos[3 * j], yj = pos[3 * j + 1], zj = pos[3 * j + 2];
                const float sqj = xj * xj + yj * yj + zj * zj;
                const float dot = sx * xj + sy * yj + sz * zj;
                const float d2  = (ssq + sqj) - 2.0f * dot;
                const float dist = sqrtf(fmaxf(d2, 0.0f));
                if (dist <= CUTOFF_F) { v = true; k = ((uint64_t)__float_as_uint(dist) << 32) | (uint32_t)j; }
            }
            const unsigned long long m = __ballot(v);
            if (v) lst[cnt + __popcll(m & ((1ULL << lane) - 1ULL))] = k;
            cnt += __popcll(m);
        }
        return cnt;
    };

    int cnt0 = 0, cnt1 = 0;
    if (b1 == b0) {
        // fused pass: one pos[j]/sqj load serves both atoms
        for (int jb = start0; jb < end0; jb += 64) {
            const int j = jb + lane;
            bool va = false, vb = false; uint64_t ka = 0, kb = 0;
            if (j < end0) {
                const float xj = pos[3 * j], yj = pos[3 * j + 1], zj = pos[3 * j + 2];
                const float sqj = xj * xj + yj * yj + zj * zj;
                if (j != i0) {
                    const float dot = x0 * xj + y0 * yj + z0 * zj;
                    const float d2  = (sq0 + sqj) - 2.0f * dot;
                    const float dist = sqrtf(fmaxf(d2, 0.0f));
                    if (dist <= CUTOFF_F) { va = true; ka = ((uint64_t)__float_as_uint(dist) << 32) | (uint32_t)j; }
                }
                if (j != i1) {
                    const float dot = x1 * xj + y1 * yj + z1 * zj;
                    const float d2  = (sq1 + sqj) - 2.0f * dot;
                    const float dist = sqrtf(fmaxf(d2, 0.0f));
                    if (dist <= CUTOFF_F) { vb = true; kb = ((uint64_t)__float_as_uint(dist) << 32) | (uint32_t)j; }
                }
            }
            const unsigned long long m0 = __ballot(va);
            if (va) list0[cnt0 + __popcll(m0 & ((1ULL << lane) - 1ULL))] = ka;
            cnt0 += __popcll(m0);
            const unsigned long long m1 = __ballot(vb);
            if (vb) list1[cnt1 + __popcll(m1 & ((1ULL << lane) - 1ULL))] = kb;
            cnt1 += __popcll(m1);
        }
    } else {
        cnt0 = process(start0, end0, i0, x0, y0, z0, sq0, list0);
        cnt1 = process(start1, end1, i1, x1, y1, z1, sq1, list1);
    }

    if (lane < KNB) { win[0][lane] = i0; win[1][lane] = i1; }   // pads: self
    __syncthreads();

    const int C0 = cnt0, C1 = cnt1;
    for (int t = lane; t < C0; t += 64) {
        const uint64_t my = list0[t]; int r = 0;
        #pragma unroll 4
        for (int u = 0; u < C0; ++u) r += (list0[u] < my) ? 1 : 0;  // broadcast reads
        if (r < KNB) win[0][r] = (int)(uint32_t)(my & 0xFFFFFFFFu);
    }
    for (int t = lane; t < C1; t += 64) {
        const uint64_t my = list1[t]; int r = 0;
        #pragma unroll 4
        for (int u = 0; u < C1; ++u) r += (list1[u] < my) ? 1 : 0;
        if (r < KNB) win[1][r] = (int)(uint32_t)(my & 0xFFFFFFFFu);
    }
    __syncthreads();

    // epilogue: 64 lanes -> 64 contiguous edges (i0*KNB .. i0*KNB+63)
    const int half = lane >> 5;
    const int slot = lane & 31;
    const int a    = i0 + half;
    const int dst  = win[half][slot];
    const int C    = half ? C1 : C0;
    const float ax = half ? x1 : x0, ay = half ? y1 : y0, az = half ? z1 : z0;
    const long long NK = (long long)N_ATOMS * KNB;
    const long long e  = (long long)a * KNB + slot;
    out[e]      = (float)a;
    out[NK + e] = (float)dst;
    // real edge: pos[dst]-pos[a]; pad: dst==a -> exactly 0.0
    out[2 * NK + 3 * e]     = pos[3 * dst]     - ax;
    out[2 * NK + 3 * e + 1] = pos[3 * dst + 1] - ay;
    out[2 * NK + 3 * e + 2] = pos[3 * dst + 2] - az;
    out[5 * NK + e] = (slot < C) ? 1.0f : 0.0f;
}

extern "C" void kernel_launch(void* const* d_in, const int* in_sizes, int n_in,
                              void* d_out, int out_size, void* d_ws, size_t ws_size,
                              hipStream_t stream) {
    const float* pos   = (const float*)d_in[0];   // [8192, 3] f32
    const int*   batch = (const int*)d_in[1];     // [8192] i32, sorted
    float*       out   = (float*)d_out;           // 6*N*K floats
    radius_graph_kernel<<<N_ATOMS / 2, 64, 0, stream>>>(pos, batch, out);
}